// Round 14
// baseline (120.821 us; speedup 1.0000x reference)
//
#include <hip/hip_runtime.h>
#include <hip/hip_bf16.h>
#include <cstddef>

#define B_    128
#define D_    2048
#define C_    16522
#define BETA_INV 20.0f      // 1/0.05
#define LSTRIDE 16528       // padded logits row stride (floats)

#define NTILES 1033         // ceil(C/16)
#define NCHUNK 8
#define CHW    2066         // ceil(C/8)

#define NCOPY  2066         // copy workers in fused_main (2 per 3 blocks)
#define NFUSED 3099         // 2066 copy + 1033 gemm, interleaved 2:1

typedef __bf16 bf16;
typedef bf16  bf16x8 __attribute__((ext_vector_type(8)));
typedef float f32x4  __attribute__((ext_vector_type(4)));

// ws layout (bytes):
//   logits : [0, 8462336)                128*16528*4
//   A_pack : [8462336, 8986624)          128*2048*2  bf16 fragment-ordered
//   part   : [8986624, 9052160)          128*8*16*4  row_loss partials
#define WS_APACK_OFF 8462336
#define WS_PART_OFF  8986624

// ---------------------------------------------------------------------------
// pack_a: inputs [128,2048] fp32 -> bf16 in MFMA A-fragment order. Separate
// launch (gemm reads apack inside fused_main — intra-kernel race otherwise).
// ---------------------------------------------------------------------------
__global__ __launch_bounds__(256) void pack_a(const float* __restrict__ inp,
                                              bf16* __restrict__ ap) {
  const int tid  = blockIdx.x * 256 + threadIdx.x;   // 0..32767
  const int lane = tid & 63;
  const int ks   = (tid >> 6) & 63;
  const int mt   = tid >> 12;
  const int row  = mt * 16 + (lane & 15);
  const int col  = ks * 32 + (lane >> 4) * 8;
  const float4 v0 = *(const float4*)(inp + row * D_ + col);
  const float4 v1 = *(const float4*)(inp + row * D_ + col + 4);
  bf16x8 b;
  b[0] = (bf16)v0.x; b[1] = (bf16)v0.y; b[2] = (bf16)v0.z; b[3] = (bf16)v0.w;
  b[4] = (bf16)v1.x; b[5] = (bf16)v1.y; b[6] = (bf16)v1.z; b[7] = (bf16)v1.w;
  ((bf16x8*)ap)[tid] = b;
}

// ---------------------------------------------------------------------------
// fused_main: copy_em + gemm_logits co-resident in ONE launch.
// R14: TRIO-LOCALITY copy assignment. Copy workers 2g,2g+1 own exactly the
// 16 em rows of gemm tile g (8 rows = 64 KB contiguous each) instead of a
// 16.9 MB-stride grid-stride walk. The trio of consecutive blocks 3g..3g+2
// touches the same 128 KB of em at the same time -> em flows HBM->L3->L2
// once with tight temporal reuse between roles (FETCH already shows em read
// exactly once; this targets the L3-BW/latency component of the wall).
// Cold-stream wall context: 6 implementations (3 hand copies, AMD blit @2.0,
// memcpy, fused variants) all cap at 2.0-2.6 TB/s visible while pure writes
// sustain 7 TB/s; the delta is the harness reset's ~528 MB of dirty L3
// lines written back under our streams (L3 is memory-side; TCC counters
// cannot see L3->HBM writebacks). NT stores measurably did NOT suppress L3
// write-allocation (R13: FETCH unchanged 134 MB) — kept only because they
// were ~2.5 µs faster than plain in the A/B.
// ---------------------------------------------------------------------------
__global__ __launch_bounds__(256, 4) void fused_main(
    const float* __restrict__ em,
    float*       __restrict__ out_em,
    const bf16*  __restrict__ ap,
    float*       __restrict__ logits)
{
  const int b  = blockIdx.x;
  const int g  = b / 3;
  const int r3 = b - g * 3;

  if (r3 < 2) {                        // ---- copy worker id = g*2+r3 ----
    const int id = g * 2 + r3;         // owns em rows [8*id, 8*id+8)
    const int t  = threadIdx.x;
    const size_t base  = (size_t)id * 4096;        // f32x4 units (8 rows)
    const size_t limit = (size_t)C_ * D_ / 4;      // 8,459,264
    const f32x4* src = (const f32x4*)em;
    f32x4*       dst = (f32x4*)out_em;
    #pragma unroll 2
    for (int k = 0; k < 16; ++k) {
      const size_t i = base + (size_t)k * 256 + t;
      if (i < limit)
        __builtin_nontemporal_store(src[i], dst + i);
    }
    return;
  }

  // ---- gemm tile g (0..1032) ----
  const int tid  = threadIdx.x;
  const int lane = tid & 63;
  const int w    = tid >> 6;          // K-quarter 0..3
  const int ml   = lane & 15;
  const int quad = lane >> 4;
  const int n0   = g * 16;
  const int r    = n0 + ml;
  const bool valid = r < C_;

  const float* bp = em + (size_t)(valid ? r : 0) * D_ + quad * 8;
  const bf16x8* af = (const bf16x8*)ap;

  const int ks0 = w * 16;

  f32x4 acc[8] = {};

  f32x4 e0a = *(const f32x4*)(bp + ks0 * 32);
  f32x4 e0b = *(const f32x4*)(bp + ks0 * 32 + 4);

  #pragma unroll 3
  for (int i = 0; i < 15; ++i) {
    const int ks = ks0 + i;
    bf16x8 A0[8];
    #pragma unroll
    for (int mt = 0; mt < 8; ++mt)
      A0[mt] = af[(mt * 64 + ks) * 64 + lane];
    const f32x4 e1a = *(const f32x4*)(bp + (ks + 1) * 32);
    const f32x4 e1b = *(const f32x4*)(bp + (ks + 1) * 32 + 4);
    bf16x8 bv;
    bv[0] = (bf16)e0a[0]; bv[1] = (bf16)e0a[1]; bv[2] = (bf16)e0a[2]; bv[3] = (bf16)e0a[3];
    bv[4] = (bf16)e0b[0]; bv[5] = (bf16)e0b[1]; bv[6] = (bf16)e0b[2]; bv[7] = (bf16)e0b[3];
    #pragma unroll
    for (int mt = 0; mt < 8; ++mt)
      acc[mt] = __builtin_amdgcn_mfma_f32_16x16x32_bf16(A0[mt], bv, acc[mt], 0, 0, 0);
    e0a = e1a; e0b = e1b;
  }
  {
    const int ks = ks0 + 15;
    bf16x8 A0[8];
    #pragma unroll
    for (int mt = 0; mt < 8; ++mt)
      A0[mt] = af[(mt * 64 + ks) * 64 + lane];
    bf16x8 bv;
    bv[0] = (bf16)e0a[0]; bv[1] = (bf16)e0a[1]; bv[2] = (bf16)e0a[2]; bv[3] = (bf16)e0a[3];
    bv[4] = (bf16)e0b[0]; bv[5] = (bf16)e0b[1]; bv[6] = (bf16)e0b[2]; bv[7] = (bf16)e0b[3];
    #pragma unroll
    for (int mt = 0; mt < 8; ++mt)
      acc[mt] = __builtin_amdgcn_mfma_f32_16x16x32_bf16(A0[mt], bv, acc[mt], 0, 0, 0);
  }

  __shared__ f32x4 red[3][8][64];     // 24 KB
  if (w > 0) {
    #pragma unroll
    for (int mt = 0; mt < 8; ++mt) red[w - 1][mt][lane] = acc[mt];
  }
  __syncthreads();
  if (w == 0 && valid) {
    #pragma unroll
    for (int mt = 0; mt < 8; ++mt) {
      f32x4 a = acc[mt];
      a += red[0][mt][lane];
      a += red[1][mt][lane];
      a += red[2][mt][lane];
      #pragma unroll
      for (int reg = 0; reg < 4; ++reg) {
        const int row = mt * 16 + quad * 4 + reg;
        logits[row * LSTRIDE + r] = a[reg] * BETA_INV;
      }
    }
  }
}

// ---------------------------------------------------------------------------
// row_loss phase A: grid = 128 rows x 8 chunks. Partial online-lse + top-6
// + label logit per chunk -> part[(b*8+c)*16].
// R14: top-6 candidate reduction parallelized across ALL 4 waves (was:
// wave 0 alone scanned 1536 LDS slots — 48/64 lanes idle + 3 waves idle,
// Common-mistake #6). Each wave reduces its own 384-slot quarter (top-6 of
// union == top-6 of per-quarter top-6s), then wave 0 merges the 24
// finalists with the proven merge-kernel shuffle pattern.
// ---------------------------------------------------------------------------
__global__ __launch_bounds__(256) void row_loss_part(
    const float* __restrict__ logits,
    const int*   __restrict__ label,
    float*       __restrict__ part)
{
  const int b = blockIdx.x >> 3;
  const int c = blockIdx.x & 7;
  const int t = threadIdx.x;
  const int lo = c * CHW;
  const int hi = (lo + CHW < C_) ? lo + CHW : C_;
  const float* row = logits + b * LSTRIDE;
  const int y = label[b];

  float m = -INFINITY, s = 0.f, ly = -INFINITY;
  float tv[6]; int ti[6];
  #pragma unroll
  for (int q = 0; q < 6; ++q) { tv[q] = -INFINITY; ti[q] = -1; }

  for (int i = lo + t; i < hi; i += 256) {
    const float v = row[i];
    if (v > m) { s = s * __expf(m - v) + 1.f; m = v; }
    else       { s += __expf(v - m); }
    if (i == y) ly = v;
    if (v > tv[5]) {
      tv[5] = v; ti[5] = i;
      #pragma unroll
      for (int q = 5; q > 0; --q)
        if (tv[q] > tv[q - 1]) {
          const float fv = tv[q]; tv[q] = tv[q - 1]; tv[q - 1] = fv;
          const int   fi = ti[q]; ti[q] = ti[q - 1]; ti[q - 1] = fi;
        }
    }
  }

  __shared__ float rm[256], rs[256];
  __shared__ float cv[1536];
  __shared__ int   ci[1536];
  __shared__ float wtv[24];
  __shared__ int   wti[24];
  __shared__ float sly;

  rm[t] = m; rs[t] = s;
  #pragma unroll
  for (int q = 0; q < 6; ++q) { cv[t * 6 + q] = tv[q]; ci[t * 6 + q] = ti[q]; }
  if (t == 0) sly = -INFINITY;
  __syncthreads();
  if (ly != -INFINITY) sly = ly;

  for (int off = 128; off >= 1; off >>= 1) {
    if (t < off) {
      const float m2 = rm[t + off], s2 = rs[t + off];
      const float M = fmaxf(rm[t], m2);
      rs[t] = rs[t] * __expf(rm[t] - M) + s2 * __expf(m2 - M);
      rm[t] = M;
    }
    __syncthreads();
  }

  // per-wave top-6 of its 384-slot quarter (slots [wv*384, wv*384+384))
  {
    const int wv = t >> 6, ln = t & 63;
    const int base = wv * 384 + ln * 6;     // this lane's 6 slots
    float otv6[6]; int oti6[6];
    for (int rr = 0; rr < 6; ++rr) {
      float bv = -INFINITY; int bi = -1, bs = -1;
      #pragma unroll
      for (int u = 0; u < 6; ++u) {
        const float v = cv[base + u];
        if (v > bv) { bv = v; bi = ci[base + u]; bs = base + u; }
      }
      #pragma unroll
      for (int off = 32; off >= 1; off >>= 1) {
        const float ov = __shfl_down(bv, off);
        const int   oi = __shfl_down(bi, off);
        const int   os = __shfl_down(bs, off);
        if (ov > bv) { bv = ov; bi = oi; bs = os; }
      }
      bv = __shfl(bv, 0); bi = __shfl(bi, 0); bs = __shfl(bs, 0);
      if (bs >= base && bs < base + 6) cv[bs] = -INFINITY;  // owner lane clears
      otv6[rr] = bv; oti6[rr] = bi;
    }
    if (ln == 0) {
      #pragma unroll
      for (int q = 0; q < 6; ++q) { wtv[wv * 6 + q] = otv6[q]; wti[wv * 6 + q] = oti6[q]; }
    }
  }
  __syncthreads();

  if (t < 64) {   // wave 0: merge 24 finalists
    const int ln = t;
    float v = (ln < 24) ? wtv[ln] : -INFINITY;
    int  idx = (ln < 24) ? wti[ln] : -1;
    float ftv[6]; int fti[6];
    for (int rr = 0; rr < 6; ++rr) {
      float bv = v; int bi = idx, bl = ln;
      #pragma unroll
      for (int off = 32; off >= 1; off >>= 1) {
        const float ov = __shfl_down(bv, off);
        const int   oi = __shfl_down(bi, off);
        const int   ol = __shfl_down(bl, off);
        if (ov > bv) { bv = ov; bi = oi; bl = ol; }
      }
      bv = __shfl(bv, 0); bi = __shfl(bi, 0); bl = __shfl(bl, 0);
      ftv[rr] = bv; fti[rr] = bi;
      if (ln == bl) v = -INFINITY;
    }
    if (ln == 0) {
      float* p = part + (size_t)(b * 8 + c) * 16;
      p[0] = rm[0]; p[1] = rs[0]; p[2] = sly;
      #pragma unroll
      for (int q = 0; q < 6; ++q) { p[4 + q] = ftv[q]; ((int*)p)[10 + q] = fti[q]; }
    }
  }
}

// ---------------------------------------------------------------------------
// tail: fused row_loss_merge (blocks 0..127) + em_update (blocks 128..255).
// ---------------------------------------------------------------------------
__global__ __launch_bounds__(256) void tail(
    const float* __restrict__ part,
    const int*   __restrict__ label,
    float*       __restrict__ out,
    const float* __restrict__ inp,
    const float* __restrict__ em,
    const int*   __restrict__ epoch,
    float*       __restrict__ out_em)
{
  __shared__ int   lbl[B_];
  __shared__ float red[4];

  if (blockIdx.x < 128) {              // ---- row_loss_merge ----
    const int b = blockIdx.x;
    const int lane = threadIdx.x;
    if (lane >= 64) return;
    const int y = label[b];

    float m = -INFINITY, s = 0.f, ly = -INFINITY;
    if (lane < 8) {
      const float* p = part + (size_t)(b * 8 + lane) * 16;
      m = p[0]; s = p[1]; ly = p[2];
    }
    float M = m, LY = ly;
    #pragma unroll
    for (int off = 32; off >= 1; off >>= 1) {
      M  = fmaxf(M,  __shfl_down(M,  off));
      LY = fmaxf(LY, __shfl_down(LY, off));
    }
    M = __shfl(M, 0); LY = __shfl(LY, 0);
    float contrib = (lane < 8) ? s * __expf(m - M) : 0.f;
    #pragma unroll
    for (int off = 32; off >= 1; off >>= 1) contrib += __shfl_down(contrib, off);
    const float S = __shfl(contrib, 0);

    float v = -INFINITY; int idx = -1;
    if (lane < 48) {
      const float* p = part + (size_t)(b * 8 + lane / 6) * 16;
      v   = p[4 + lane % 6];
      idx = ((const int*)p)[10 + lane % 6];
    }
    float stop = 0.f; int intop = 0;
    for (int rr = 0; rr < 6; ++rr) {
      float bv = v; int bi = idx, bl = lane;
      #pragma unroll
      for (int off = 32; off >= 1; off >>= 1) {
        const float ov = __shfl_down(bv, off);
        const int   oi = __shfl_down(bi, off);
        const int   ol = __shfl_down(bl, off);
        if (ov > bv) { bv = ov; bi = oi; bl = ol; }
      }
      bv = __shfl(bv, 0); bi = __shfl(bi, 0); bl = __shfl(bl, 0);
      stop += bv;
      if (bi == y) intop = 1;
      if (lane == bl) v = -INFINITY;
    }

    if (lane == 0) {
      const float lse = M + logf(S);
      const float loss = intop ? (13.f * lse - LY - 2.f * stop)
                               : (15.f * lse - 3.f * LY - 2.f * stop);
      atomicAdd(out, loss * (1.0f / 128.0f));
    }
    return;
  }

  // ---- em_update (block 128+i) ----
  const int t = threadIdx.x;
  if (t < B_) lbl[t] = label[t];
  __syncthreads();

  const int i = blockIdx.x - 128;
  const int y = lbl[i];
  for (int j = 0; j < i; ++j)
    if (lbl[j] == y) return;            // uniform: all threads agree

  const float alpha = 0.01f * (float)epoch[0];
  const int lane = t & 63, wave = t >> 6;

  float r[8];
  #pragma unroll
  for (int u = 0; u < 8; ++u) r[u] = em[(size_t)y * D_ + t + u * 256];

  for (int j = i; j < B_; ++j) {
    if (lbl[j] != y) continue;          // uniform branch
    const float* x = inp + j * D_;
    float ss = 0.f;
    #pragma unroll
    for (int u = 0; u < 8; ++u) {
      r[u] = alpha * r[u] + (1.f - alpha) * x[t + u * 256];
      ss += r[u] * r[u];
    }
    #pragma unroll
    for (int off = 32; off >= 1; off >>= 1) ss += __shfl_down(ss, off);
    if (lane == 0) red[wave] = ss;
    __syncthreads();
    const float inv = 1.f / sqrtf(red[0] + red[1] + red[2] + red[3]);
    #pragma unroll
    for (int u = 0; u < 8; ++u) r[u] *= inv;
    __syncthreads();                    // red[] reused next chain step
  }

  #pragma unroll
  for (int u = 0; u < 8; ++u) out_em[(size_t)y * D_ + t + u * 256] = r[u];
}

// ---------------------------------------------------------------------------
// R14 pipeline: pack_a -> fused_main (trio-local copy ∥ gemm) ->
// row_loss_part (4-wave top-6) -> tail.
// ---------------------------------------------------------------------------
extern "C" void kernel_launch(void* const* d_in, const int* in_sizes, int n_in,
                              void* d_out, int out_size, void* d_ws, size_t ws_size,
                              hipStream_t stream) {
  const float* inp   = (const float*)d_in[0];
  const int*   label = (const int*)d_in[1];
  const float* em    = (const float*)d_in[2];
  const int*   epoch = (const int*)d_in[3];

  float* out    = (float*)d_out;
  float* out_em = out + 1;
  float* logits = (float*)d_ws;
  bf16*  apack  = (bf16*)((char*)d_ws + WS_APACK_OFF);
  float* part   = (float*)((char*)d_ws + WS_PART_OFF);

  hipMemsetAsync(d_out, 0, sizeof(float), stream);   // zero the loss slot

  pack_a        <<<dim3(128),        dim3(256), 0, stream>>>(inp, apack);
  fused_main    <<<dim3(NFUSED),     dim3(256), 0, stream>>>(em, out_em, apack, logits);
  row_loss_part <<<dim3(B_ * NCHUNK),dim3(256), 0, stream>>>(logits, label, part);
  tail          <<<dim3(256),        dim3(256), 0, stream>>>(part, label, out, inp, em, epoch, out_em);
}

// Round 15
// 118.052 us; speedup vs baseline: 1.0235x; 1.0235x over previous
//
#include <hip/hip_runtime.h>
#include <hip/hip_bf16.h>
#include <cstddef>

#define B_    128
#define D_    2048
#define C_    16522
#define BETA_INV 20.0f      // 1/0.05
#define LSTRIDE 16528       // padded logits row stride (floats)

#define NTILES 1033         // ceil(C/16)
#define NCHUNK 8
#define CHW    2066         // ceil(C/8)

#define NCOPY  2066         // copy workers in fused_main (2 per 3 blocks)
#define NFUSED 3099         // 2066 copy + 1033 gemm, interleaved 2:1

typedef __bf16 bf16;
typedef bf16  bf16x8 __attribute__((ext_vector_type(8)));
typedef float f32x4  __attribute__((ext_vector_type(4)));

// ws layout (bytes):
//   logits : [0, 8462336)                128*16528*4
//   A_pack : [8462336, 8986624)          128*2048*2  bf16 fragment-ordered
//   part   : [8986624, 9052160)          128*8*16*4  row_loss partials
#define WS_APACK_OFF 8462336
#define WS_PART_OFF  8986624

// ---------------------------------------------------------------------------
// pack_a: inputs [128,2048] fp32 -> bf16 in MFMA A-fragment order. Separate
// launch (gemm reads apack inside fused_main — intra-kernel race otherwise).
// ---------------------------------------------------------------------------
__global__ __launch_bounds__(256) void pack_a(const float* __restrict__ inp,
                                              bf16* __restrict__ ap) {
  const int tid  = blockIdx.x * 256 + threadIdx.x;   // 0..32767
  const int lane = tid & 63;
  const int ks   = (tid >> 6) & 63;
  const int mt   = tid >> 12;
  const int row  = mt * 16 + (lane & 15);
  const int col  = ks * 32 + (lane >> 4) * 8;
  const float4 v0 = *(const float4*)(inp + row * D_ + col);
  const float4 v1 = *(const float4*)(inp + row * D_ + col + 4);
  bf16x8 b;
  b[0] = (bf16)v0.x; b[1] = (bf16)v0.y; b[2] = (bf16)v0.z; b[3] = (bf16)v0.w;
  b[4] = (bf16)v1.x; b[5] = (bf16)v1.y; b[6] = (bf16)v1.z; b[7] = (bf16)v1.w;
  ((bf16x8*)ap)[tid] = b;
}

// ---------------------------------------------------------------------------
// fused_main: copy_em + gemm_logits co-resident in ONE launch.
// R15 = R13's proven copy assignment (grid-stride, 109.5 µs) — R14's
// trio-locality variant REVERTED (it regressed to ~114.5: 16 fixed 1KB-
// stride bursts have less outstanding-request diversity than the grid-
// stride walk, and L3-feed was never the binding constraint).
// Cold-stream wall context: 6 implementations (3 hand copies, AMD blit @2.0,
// memcpy, fused variants) all cap at 2.0-2.6 TB/s visible while pure writes
// sustain 7 TB/s; the delta is the harness reset's ~528 MB of dirty L3
// lines written back under our streams (L3 is memory-side; TCC counters
// cannot see L3->HBM writebacks). NT stores did NOT suppress L3 write-
// allocation (R13: FETCH unchanged 134 MB) — kept only as marginally
// faster in the A/B.
// ---------------------------------------------------------------------------
__global__ __launch_bounds__(256, 4) void fused_main(
    const float* __restrict__ em,
    float*       __restrict__ out_em,
    const bf16*  __restrict__ ap,
    float*       __restrict__ logits)
{
  const int b  = blockIdx.x;
  const int g  = b / 3;
  const int r3 = b - g * 3;

  if (r3 < 2) {                        // ---- copy worker id = g*2+r3 ----
    const int id = g * 2 + r3;
    const int t  = threadIdx.x;
    const size_t n = (size_t)C_ * D_ / 4;          // 8,459,264 float4
    const size_t stride = (size_t)NCOPY * 512;
    for (size_t i = (size_t)id * 512 + t; i < n; i += stride) {
      const f32x4 v0 = ((const f32x4*)em)[i];
      const bool  h1 = (i + 256) < n;
      f32x4 v1 = {};
      if (h1) v1 = ((const f32x4*)em)[i + 256];
      __builtin_nontemporal_store(v0, ((f32x4*)out_em) + i);
      if (h1) __builtin_nontemporal_store(v1, ((f32x4*)out_em) + i + 256);
    }
    return;
  }

  // ---- gemm tile g (0..1032) ----
  const int tid  = threadIdx.x;
  const int lane = tid & 63;
  const int w    = tid >> 6;          // K-quarter 0..3
  const int ml   = lane & 15;
  const int quad = lane >> 4;
  const int n0   = g * 16;
  const int r    = n0 + ml;
  const bool valid = r < C_;

  const float* bp = em + (size_t)(valid ? r : 0) * D_ + quad * 8;
  const bf16x8* af = (const bf16x8*)ap;

  const int ks0 = w * 16;

  f32x4 acc[8] = {};

  f32x4 e0a = *(const f32x4*)(bp + ks0 * 32);
  f32x4 e0b = *(const f32x4*)(bp + ks0 * 32 + 4);

  #pragma unroll 3
  for (int i = 0; i < 15; ++i) {
    const int ks = ks0 + i;
    bf16x8 A0[8];
    #pragma unroll
    for (int mt = 0; mt < 8; ++mt)
      A0[mt] = af[(mt * 64 + ks) * 64 + lane];
    const f32x4 e1a = *(const f32x4*)(bp + (ks + 1) * 32);
    const f32x4 e1b = *(const f32x4*)(bp + (ks + 1) * 32 + 4);
    bf16x8 bv;
    bv[0] = (bf16)e0a[0]; bv[1] = (bf16)e0a[1]; bv[2] = (bf16)e0a[2]; bv[3] = (bf16)e0a[3];
    bv[4] = (bf16)e0b[0]; bv[5] = (bf16)e0b[1]; bv[6] = (bf16)e0b[2]; bv[7] = (bf16)e0b[3];
    #pragma unroll
    for (int mt = 0; mt < 8; ++mt)
      acc[mt] = __builtin_amdgcn_mfma_f32_16x16x32_bf16(A0[mt], bv, acc[mt], 0, 0, 0);
    e0a = e1a; e0b = e1b;
  }
  {
    const int ks = ks0 + 15;
    bf16x8 A0[8];
    #pragma unroll
    for (int mt = 0; mt < 8; ++mt)
      A0[mt] = af[(mt * 64 + ks) * 64 + lane];
    bf16x8 bv;
    bv[0] = (bf16)e0a[0]; bv[1] = (bf16)e0a[1]; bv[2] = (bf16)e0a[2]; bv[3] = (bf16)e0a[3];
    bv[4] = (bf16)e0b[0]; bv[5] = (bf16)e0b[1]; bv[6] = (bf16)e0b[2]; bv[7] = (bf16)e0b[3];
    #pragma unroll
    for (int mt = 0; mt < 8; ++mt)
      acc[mt] = __builtin_amdgcn_mfma_f32_16x16x32_bf16(A0[mt], bv, acc[mt], 0, 0, 0);
  }

  __shared__ f32x4 red[3][8][64];     // 24 KB
  if (w > 0) {
    #pragma unroll
    for (int mt = 0; mt < 8; ++mt) red[w - 1][mt][lane] = acc[mt];
  }
  __syncthreads();
  if (w == 0 && valid) {
    #pragma unroll
    for (int mt = 0; mt < 8; ++mt) {
      f32x4 a = acc[mt];
      a += red[0][mt][lane];
      a += red[1][mt][lane];
      a += red[2][mt][lane];
      #pragma unroll
      for (int reg = 0; reg < 4; ++reg) {
        const int row = mt * 16 + quad * 4 + reg;
        logits[row * LSTRIDE + r] = a[reg] * BETA_INV;
      }
    }
  }
}

// ---------------------------------------------------------------------------
// row_loss phase A: grid = 128 rows x 8 chunks. Partial online-lse + top-6
// + label logit per chunk -> part[(b*8+c)*16].
// R14's 4-wave top-6 KEPT: each wave reduces its own 384-slot quarter
// (top-6 of union == top-6 of per-quarter top-6s), wave 0 merges 24
// finalists. (Old: wave 0 alone scanned 1536 slots, 48/64 lanes idle.)
// ---------------------------------------------------------------------------
__global__ __launch_bounds__(256) void row_loss_part(
    const float* __restrict__ logits,
    const int*   __restrict__ label,
    float*       __restrict__ part)
{
  const int b = blockIdx.x >> 3;
  const int c = blockIdx.x & 7;
  const int t = threadIdx.x;
  const int lo = c * CHW;
  const int hi = (lo + CHW < C_) ? lo + CHW : C_;
  const float* row = logits + b * LSTRIDE;
  const int y = label[b];

  float m = -INFINITY, s = 0.f, ly = -INFINITY;
  float tv[6]; int ti[6];
  #pragma unroll
  for (int q = 0; q < 6; ++q) { tv[q] = -INFINITY; ti[q] = -1; }

  for (int i = lo + t; i < hi; i += 256) {
    const float v = row[i];
    if (v > m) { s = s * __expf(m - v) + 1.f; m = v; }
    else       { s += __expf(v - m); }
    if (i == y) ly = v;
    if (v > tv[5]) {
      tv[5] = v; ti[5] = i;
      #pragma unroll
      for (int q = 5; q > 0; --q)
        if (tv[q] > tv[q - 1]) {
          const float fv = tv[q]; tv[q] = tv[q - 1]; tv[q - 1] = fv;
          const int   fi = ti[q]; ti[q] = ti[q - 1]; ti[q - 1] = fi;
        }
    }
  }

  __shared__ float rm[256], rs[256];
  __shared__ float cv[1536];
  __shared__ int   ci[1536];
  __shared__ float wtv[24];
  __shared__ int   wti[24];
  __shared__ float sly;

  rm[t] = m; rs[t] = s;
  #pragma unroll
  for (int q = 0; q < 6; ++q) { cv[t * 6 + q] = tv[q]; ci[t * 6 + q] = ti[q]; }
  if (t == 0) sly = -INFINITY;
  __syncthreads();
  if (ly != -INFINITY) sly = ly;

  for (int off = 128; off >= 1; off >>= 1) {
    if (t < off) {
      const float m2 = rm[t + off], s2 = rs[t + off];
      const float M = fmaxf(rm[t], m2);
      rs[t] = rs[t] * __expf(rm[t] - M) + s2 * __expf(m2 - M);
      rm[t] = M;
    }
    __syncthreads();
  }

  // per-wave top-6 of its 384-slot quarter (slots [wv*384, wv*384+384))
  {
    const int wv = t >> 6, ln = t & 63;
    const int base = wv * 384 + ln * 6;     // this lane's 6 slots
    float otv6[6]; int oti6[6];
    for (int rr = 0; rr < 6; ++rr) {
      float bv = -INFINITY; int bi = -1, bs = -1;
      #pragma unroll
      for (int u = 0; u < 6; ++u) {
        const float v = cv[base + u];
        if (v > bv) { bv = v; bi = ci[base + u]; bs = base + u; }
      }
      #pragma unroll
      for (int off = 32; off >= 1; off >>= 1) {
        const float ov = __shfl_down(bv, off);
        const int   oi = __shfl_down(bi, off);
        const int   os = __shfl_down(bs, off);
        if (ov > bv) { bv = ov; bi = oi; bs = os; }
      }
      bv = __shfl(bv, 0); bi = __shfl(bi, 0); bs = __shfl(bs, 0);
      if (bs >= base && bs < base + 6) cv[bs] = -INFINITY;  // owner lane clears
      otv6[rr] = bv; oti6[rr] = bi;
    }
    if (ln == 0) {
      #pragma unroll
      for (int q = 0; q < 6; ++q) { wtv[wv * 6 + q] = otv6[q]; wti[wv * 6 + q] = oti6[q]; }
    }
  }
  __syncthreads();

  if (t < 64) {   // wave 0: merge 24 finalists
    const int ln = t;
    float v = (ln < 24) ? wtv[ln] : -INFINITY;
    int  idx = (ln < 24) ? wti[ln] : -1;
    float ftv[6]; int fti[6];
    for (int rr = 0; rr < 6; ++rr) {
      float bv = v; int bi = idx, bl = ln;
      #pragma unroll
      for (int off = 32; off >= 1; off >>= 1) {
        const float ov = __shfl_down(bv, off);
        const int   oi = __shfl_down(bi, off);
        const int   ol = __shfl_down(bl, off);
        if (ov > bv) { bv = ov; bi = oi; bl = ol; }
      }
      bv = __shfl(bv, 0); bi = __shfl(bi, 0); bl = __shfl(bl, 0);
      ftv[rr] = bv; fti[rr] = bi;
      if (ln == bl) v = -INFINITY;
    }
    if (ln == 0) {
      float* p = part + (size_t)(b * 8 + c) * 16;
      p[0] = rm[0]; p[1] = rs[0]; p[2] = sly;
      #pragma unroll
      for (int q = 0; q < 6; ++q) { p[4 + q] = ftv[q]; ((int*)p)[10 + q] = fti[q]; }
    }
  }
}

// ---------------------------------------------------------------------------
// tail: fused row_loss_merge (blocks 0..127) + em_update (blocks 128..255).
// ---------------------------------------------------------------------------
__global__ __launch_bounds__(256) void tail(
    const float* __restrict__ part,
    const int*   __restrict__ label,
    float*       __restrict__ out,
    const float* __restrict__ inp,
    const float* __restrict__ em,
    const int*   __restrict__ epoch,
    float*       __restrict__ out_em)
{
  __shared__ int   lbl[B_];
  __shared__ float red[4];

  if (blockIdx.x < 128) {              // ---- row_loss_merge ----
    const int b = blockIdx.x;
    const int lane = threadIdx.x;
    if (lane >= 64) return;
    const int y = label[b];

    float m = -INFINITY, s = 0.f, ly = -INFINITY;
    if (lane < 8) {
      const float* p = part + (size_t)(b * 8 + lane) * 16;
      m = p[0]; s = p[1]; ly = p[2];
    }
    float M = m, LY = ly;
    #pragma unroll
    for (int off = 32; off >= 1; off >>= 1) {
      M  = fmaxf(M,  __shfl_down(M,  off));
      LY = fmaxf(LY, __shfl_down(LY, off));
    }
    M = __shfl(M, 0); LY = __shfl(LY, 0);
    float contrib = (lane < 8) ? s * __expf(m - M) : 0.f;
    #pragma unroll
    for (int off = 32; off >= 1; off >>= 1) contrib += __shfl_down(contrib, off);
    const float S = __shfl(contrib, 0);

    float v = -INFINITY; int idx = -1;
    if (lane < 48) {
      const float* p = part + (size_t)(b * 8 + lane / 6) * 16;
      v   = p[4 + lane % 6];
      idx = ((const int*)p)[10 + lane % 6];
    }
    float stop = 0.f; int intop = 0;
    for (int rr = 0; rr < 6; ++rr) {
      float bv = v; int bi = idx, bl = lane;
      #pragma unroll
      for (int off = 32; off >= 1; off >>= 1) {
        const float ov = __shfl_down(bv, off);
        const int   oi = __shfl_down(bi, off);
        const int   ol = __shfl_down(bl, off);
        if (ov > bv) { bv = ov; bi = oi; bl = ol; }
      }
      bv = __shfl(bv, 0); bi = __shfl(bi, 0); bl = __shfl(bl, 0);
      stop += bv;
      if (bi == y) intop = 1;
      if (lane == bl) v = -INFINITY;
    }

    if (lane == 0) {
      const float lse = M + logf(S);
      const float loss = intop ? (13.f * lse - LY - 2.f * stop)
                               : (15.f * lse - 3.f * LY - 2.f * stop);
      atomicAdd(out, loss * (1.0f / 128.0f));
    }
    return;
  }

  // ---- em_update (block 128+i) ----
  const int t = threadIdx.x;
  if (t < B_) lbl[t] = label[t];
  __syncthreads();

  const int i = blockIdx.x - 128;
  const int y = lbl[i];
  for (int j = 0; j < i; ++j)
    if (lbl[j] == y) return;            // uniform: all threads agree

  const float alpha = 0.01f * (float)epoch[0];
  const int lane = t & 63, wave = t >> 6;

  float r[8];
  #pragma unroll
  for (int u = 0; u < 8; ++u) r[u] = em[(size_t)y * D_ + t + u * 256];

  for (int j = i; j < B_; ++j) {
    if (lbl[j] != y) continue;          // uniform branch
    const float* x = inp + j * D_;
    float ss = 0.f;
    #pragma unroll
    for (int u = 0; u < 8; ++u) {
      r[u] = alpha * r[u] + (1.f - alpha) * x[t + u * 256];
      ss += r[u] * r[u];
    }
    #pragma unroll
    for (int off = 32; off >= 1; off >>= 1) ss += __shfl_down(ss, off);
    if (lane == 0) red[wave] = ss;
    __syncthreads();
    const float inv = 1.f / sqrtf(red[0] + red[1] + red[2] + red[3]);
    #pragma unroll
    for (int u = 0; u < 8; ++u) r[u] *= inv;
    __syncthreads();                    // red[] reused next chain step
  }

  #pragma unroll
  for (int u = 0; u < 8; ++u) out_em[(size_t)y * D_ + t + u * 256] = r[u];
}

// ---------------------------------------------------------------------------
// R15 pipeline (best-of): pack_a -> fused_main (R13 grid-stride copy ∥ gemm)
// -> row_loss_part (R14 4-wave top-6) -> tail.
// ---------------------------------------------------------------------------
extern "C" void kernel_launch(void* const* d_in, const int* in_sizes, int n_in,
                              void* d_out, int out_size, void* d_ws, size_t ws_size,
                              hipStream_t stream) {
  const float* inp   = (const float*)d_in[0];
  const int*   label = (const int*)d_in[1];
  const float* em    = (const float*)d_in[2];
  const int*   epoch = (const int*)d_in[3];

  float* out    = (float*)d_out;
  float* out_em = out + 1;
  float* logits = (float*)d_ws;
  bf16*  apack  = (bf16*)((char*)d_ws + WS_APACK_OFF);
  float* part   = (float*)((char*)d_ws + WS_PART_OFF);

  hipMemsetAsync(d_out, 0, sizeof(float), stream);   // zero the loss slot

  pack_a        <<<dim3(128),        dim3(256), 0, stream>>>(inp, apack);
  fused_main    <<<dim3(NFUSED),     dim3(256), 0, stream>>>(em, out_em, apack, logits);
  row_loss_part <<<dim3(B_ * NCHUNK),dim3(256), 0, stream>>>(logits, label, part);
  tail          <<<dim3(256),        dim3(256), 0, stream>>>(part, label, out, inp, em, epoch, out_em);
}